// Round 8
// baseline (102.515 us; speedup 1.0000x reference)
//
#include <hip/hip_runtime.h>
#include <math.h>

#define N_PTR 2048
#define M_NU  4096
#define DIM   512
#define KCLS  1000
#define KPAD  1024

static constexpr float LAMBDA_ = 0.1f;
static constexpr float EPS_ = 1e-8f;
static constexpr float INV_DENOM = 1.0f / (0.1f * 0.5f + 1e-8f);   // 1/(lambda*eps+EPS)

typedef short short8 __attribute__((ext_vector_type(8)));
typedef unsigned short u16x8 __attribute__((ext_vector_type(8)));
typedef unsigned short u16x4 __attribute__((ext_vector_type(4)));
typedef float f32x4 __attribute__((ext_vector_type(4)));

__device__ __forceinline__ unsigned short f2bf(float x) {
  unsigned u = __float_as_uint(x);
  u += 0x7fff + ((u >> 16) & 1);     // round-to-nearest-even
  return (unsigned short)(u >> 16);
}
__device__ __forceinline__ float bf2f(unsigned short h) {
  return __uint_as_float(((unsigned)h) << 16);
}

__device__ __forceinline__ void gload16(const void* g, void* l) {
  __builtin_amdgcn_global_load_lds(
      (const __attribute__((address_space(1))) unsigned int*)g,
      (__attribute__((address_space(3))) unsigned int*)l, 16, 0, 0);
}

// ---------- block reduction helpers (blockDim.x == 256) ----------
__device__ __forceinline__ float blk_reduce_sum(float v, float* red) {
  #pragma unroll
  for (int off = 32; off > 0; off >>= 1) v += __shfl_down(v, off);
  __syncthreads();
  if ((threadIdx.x & 63) == 0) red[threadIdx.x >> 6] = v;
  __syncthreads();
  return red[0] + red[1] + red[2] + red[3];
}

__device__ __forceinline__ float blk_reduce_max(float v, float* red) {
  #pragma unroll
  for (int off = 32; off > 0; off >>= 1) v = fmaxf(v, __shfl_down(v, off));
  __syncthreads();
  if ((threadIdx.x & 63) == 0) red[threadIdx.x >> 6] = v;
  __syncthreads();
  return fmaxf(fmaxf(red[0], red[1]), fmaxf(red[2], red[3]));
}

// ---------- 1. fused prep: normalize+cast (blocks 0..1791) + CE loss (blocks 1792..5887) ----------
__global__ __launch_bounds__(256) void prep_kernel(
    const float* __restrict__ ptr_f, const float* __restrict__ nu_f,
    const float* __restrict__ cls_f, const float* __restrict__ logits,
    const int* __restrict__ labels, unsigned short* __restrict__ An,
    unsigned short* __restrict__ Bn, unsigned short* __restrict__ Cn,
    float* __restrict__ losses) {
  __shared__ float red[4];
  int b = blockIdx.x;
  int tid = threadIdx.x;
  if (b < 1792) {                       // ---- normalize + bf16 cast, one wave per row
    int gid = b * 256 + tid;
    int row = gid >> 6, lane = gid & 63;
    const float* src; unsigned short* dst; int lrow; int in_rows;
    if (row < N_PTR)             { src = ptr_f; dst = An; lrow = row;                in_rows = N_PTR; }
    else if (row < N_PTR + M_NU) { src = nu_f;  dst = Bn; lrow = row - N_PTR;        in_rows = M_NU; }
    else                         { src = cls_f; dst = Cn; lrow = row - N_PTR - M_NU; in_rows = KCLS; }
    u16x8 ov;
    if (lrow < in_rows) {
      const float4* rp = (const float4*)(src + (size_t)lrow * DIM);
      float4 a = rp[lane * 2], bq = rp[lane * 2 + 1];
      float v[8] = {a.x, a.y, a.z, a.w, bq.x, bq.y, bq.z, bq.w};
      float s = 0.f;
      #pragma unroll
      for (int j = 0; j < 8; ++j) s = fmaf(v[j], v[j], s);
      #pragma unroll
      for (int off = 32; off > 0; off >>= 1) s += __shfl_xor(s, off);
      float inv = 1.0f / fmaxf(sqrtf(s), EPS_);
      #pragma unroll
      for (int j = 0; j < 8; ++j) ov[j] = f2bf(v[j] * inv);
    } else {
      #pragma unroll
      for (int j = 0; j < 8; ++j) ov[j] = 0;
    }
    *(u16x8*)(dst + (size_t)lrow * DIM + lane * 8) = ov;
  } else {                              // ---- CE loss (one block per nu row, float4 reads)
    int row = b - 1792;
    const float* x = logits + (size_t)row * KCLS;
    const float4* x4 = (const float4*)x;          // 4000B rows are 16B-aligned
    float4 v = make_float4(0.f, 0.f, 0.f, 0.f);
    float mx_loc = -INFINITY;
    if (tid < 250) {                              // 250*4 = 1000
      v = x4[tid];
      mx_loc = fmaxf(fmaxf(v.x, v.y), fmaxf(v.z, v.w));
    }
    float mx = blk_reduce_max(mx_loc, red);
    float se_loc = 0.f;
    if (tid < 250)
      se_loc = __expf(v.x - mx) + __expf(v.y - mx) + __expf(v.z - mx) + __expf(v.w - mx);
    float se = blk_reduce_sum(se_loc, red);
    if (tid == 0) losses[row] = mx + logf(se) - x[labels[row]];
  }
}

// ---------- 2. pure bf16 MFMA GEMM (transposed output, 8B stores) ----------
// acc = mfma(B-frag, A-frag): out-row n = lane&15, out-cols = (lane>>4)*4 + reg.
// EXTRA=1 (G-launch): blocks >= GX*16 do colsum partials (96) + gmax (1).
template <int BM, int GX, int EXTRA>
__global__ __launch_bounds__(256) void gemm_kernel(
    const unsigned short* __restrict__ A, const unsigned short* __restrict__ B,
    unsigned short* __restrict__ C, int ldc,
    const unsigned short* __restrict__ An, const unsigned short* __restrict__ Bn,
    const unsigned short* __restrict__ Cn,
    const int* __restrict__ pl, const int* __restrict__ nl,
    const float* __restrict__ nloss, float* __restrict__ csum_part,
    unsigned* __restrict__ gbits) {
  constexpr int FR = BM / 32;
  constexpr int WSPAN = BM / 2;
  constexpr int NTILES = GX * 16;
  const int b = blockIdx.x;
  const int tid = threadIdx.x;

  if (EXTRA && b >= NTILES) {          // ---- colsum partials + gmax
    int j = b - NTILES;                // 0..96
    __shared__ float red[4];
    if (j == 96) {
      float mloc = 0.f;
      for (int i = tid; i < M_NU; i += 256) mloc = fmaxf(mloc, nloss[i]);
      float mx = blk_reduce_max(mloc, red);
      if (tid == 0) *gbits = __float_as_uint(mx);
      return;
    }
    const unsigned short* basep; const int* idx = nullptr; int n0;
    if (j < 16)      { basep = An; n0 = j * 128; }
    else if (j < 48) { basep = Bn; n0 = (j - 16) * 128; }
    else if (j < 64) { basep = Cn; idx = pl; n0 = (j - 48) * 128; }
    else             { basep = Cn; idx = nl; n0 = (j - 64) * 128; }
    float a0 = 0.f, a1 = 0.f;
    for (int i = 0; i < 128; ++i) {
      int rr = n0 + i;
      const unsigned short* rowp = basep + (size_t)(idx ? idx[rr] : rr) * DIM;
      unsigned v = *(const unsigned*)(rowp + tid * 2);
      a0 += bf2f((unsigned short)(v & 0xffffu));
      a1 += bf2f((unsigned short)(v >> 16));
    }
    csum_part[(size_t)j * DIM + tid * 2]     = a0;
    csum_part[(size_t)j * DIM + tid * 2 + 1] = a1;
    return;
  }

  __shared__ unsigned short Alds[BM * 64];
  __shared__ unsigned short Blds[BM * 64];
  const int w = tid >> 6, lane = tid & 63;
  const int bcol = (b % GX) * BM, brow = (b / GX) * BM;
  const int wr = w >> 1, wc = w & 1;

  const int sr = lane >> 3;            // row within 8-row staging group
  const int sc = lane & 7;             // 16B chunk within 128B row
  const int schunk = (sc ^ sr) * 8;    // pre-swizzled global element offset

  f32x4 acc[FR][FR] = {};

  for (int k0 = 0; k0 < DIM; k0 += 64) {
    #pragma unroll
    for (int i = 0; i < FR; ++i) {
      int j = w * FR + i;              // staging slot, 8 rows each
      int r = j * 8 + sr;
      gload16(A + (size_t)(brow + r) * DIM + k0 + schunk, (char*)Alds + j * 1024);
      gload16(B + (size_t)(bcol + r) * DIM + k0 + schunk, (char*)Blds + j * 1024);
    }
    __syncthreads();
    #pragma unroll
    for (int kk = 0; kk < 2; ++kk) {
      const int koff = kk * 64 + (lane >> 4) * 16;
      short8 af[FR], bfr[FR];
      #pragma unroll
      for (int mi = 0; mi < FR; ++mi) {
        int r = wr * WSPAN + mi * 16 + (lane & 15);
        af[mi] = *(const short8*)((const char*)Alds + r * 128 + (koff ^ ((r & 7) << 4)));
      }
      #pragma unroll
      for (int ni = 0; ni < FR; ++ni) {
        int r = wc * WSPAN + ni * 16 + (lane & 15);
        bfr[ni] = *(const short8*)((const char*)Blds + r * 128 + (koff ^ ((r & 7) << 4)));
      }
      #pragma unroll
      for (int mi = 0; mi < FR; ++mi)
        #pragma unroll
        for (int ni = 0; ni < FR; ++ni)
          acc[mi][ni] = __builtin_amdgcn_mfma_f32_16x16x32_bf16(bfr[ni], af[mi], acc[mi][ni], 0, 0, 0);
    }
    __syncthreads();
  }

  // store-only epilogue: row n = lane&15 pattern, 4 consecutive cols per reg quad
  #pragma unroll
  for (int mi = 0; mi < FR; ++mi) {
    int n = brow + wr * WSPAN + mi * 16 + (lane & 15);
    #pragma unroll
    for (int ni = 0; ni < FR; ++ni) {
      int mb = bcol + wc * WSPAN + ni * 16 + ((lane >> 4) << 2);
      u16x4 o;
      #pragma unroll
      for (int j = 0; j < 4; ++j) o[j] = f2bf(acc[mi][ni][j]);
      *(u16x4*)(C + (size_t)n * ldc + mb) = o;
    }
  }
}

// ---------- 3. rowpass: one wave per n; G-row staged in LDS; in-place s -> t ----------
// t = exp((loss_m - gmax - lambda*(2 - s - gy)) * INV); winv/trow/drow per row.
__global__ __launch_bounds__(256) void rowpass_kernel(
    unsigned short* __restrict__ Sb, const unsigned short* __restrict__ Gfb,
    const int* __restrict__ pl, const int* __restrict__ nl,
    const float* __restrict__ nloss, const unsigned* __restrict__ gbits,
    float* __restrict__ winv, float* __restrict__ trow, float* __restrict__ drow) {
  __shared__ unsigned short Gld[4][KPAD];     // 8 KB: one 2KB G-row per wave
  const int wv = threadIdx.x >> 6, lane = threadIdx.x & 63;
  const int n = blockIdx.x * 4 + wv;
  const float gmax = __uint_as_float(*gbits);
  const float fac = LAMBDA_ * INV_DENOM;
  const float csh = gmax + 2.f * LAMBDA_;
  const unsigned short* Grow = Gfb + (size_t)pl[n] * KPAD;
  *(u16x8*)(&Gld[wv][lane * 16])     = *(const u16x8*)(Grow + lane * 16);
  *(u16x8*)(&Gld[wv][lane * 16 + 8]) = *(const u16x8*)(Grow + lane * 16 + 8);
  __syncthreads();
  unsigned short* Srow = Sb + (size_t)n * M_NU;
  float rs = 0.f, rl = 0.f;
  #pragma unroll
  for (int it = 0; it < 4; ++it) {
    const int m0 = it * 1024 + lane * 16;
    u16x8 s0 = *(const u16x8*)(Srow + m0);
    u16x8 s1 = *(const u16x8*)(Srow + m0 + 8);
    int4 n0v = *(const int4*)(nl + m0);
    int4 n1v = *(const int4*)(nl + m0 + 4);
    int4 n2v = *(const int4*)(nl + m0 + 8);
    int4 n3v = *(const int4*)(nl + m0 + 12);
    float4 l0 = *(const float4*)(nloss + m0);
    float4 l1 = *(const float4*)(nloss + m0 + 4);
    float4 l2 = *(const float4*)(nloss + m0 + 8);
    float4 l3 = *(const float4*)(nloss + m0 + 12);
    const int nli[16] = {n0v.x, n0v.y, n0v.z, n0v.w, n1v.x, n1v.y, n1v.z, n1v.w,
                         n2v.x, n2v.y, n2v.z, n2v.w, n3v.x, n3v.y, n3v.z, n3v.w};
    const float li[16] = {l0.x, l0.y, l0.z, l0.w, l1.x, l1.y, l1.z, l1.w,
                          l2.x, l2.y, l2.z, l2.w, l3.x, l3.y, l3.z, l3.w};
    u16x8 t0, t1;
    #pragma unroll
    for (int j = 0; j < 8; ++j) {
      float gy = bf2f(Gld[wv][nli[j]]);
      float t  = __expf(fmaf(fac, bf2f(s0[j]) + gy, (li[j] - csh) * INV_DENOM));
      t0[j] = f2bf(t);
      float tt = bf2f(t0[j]);
      rs += tt; rl += tt * li[j];
    }
    #pragma unroll
    for (int j = 0; j < 8; ++j) {
      float gy = bf2f(Gld[wv][nli[8 + j]]);
      float t  = __expf(fmaf(fac, bf2f(s1[j]) + gy, (li[8 + j] - csh) * INV_DENOM));
      t1[j] = f2bf(t);
      float tt = bf2f(t1[j]);
      rs += tt; rl += tt * li[8 + j];
    }
    *(u16x8*)(Srow + m0)     = t0;
    *(u16x8*)(Srow + m0 + 8) = t1;
  }
  #pragma unroll
  for (int off = 32; off > 0; off >>= 1) {
    rs += __shfl_xor(rs, off);
    rl += __shfl_xor(rl, off);
  }
  if (lane == 0) {
    float wi = 1.0f / (rs + EPS_);
    winv[n] = wi;
    trow[n] = rs * wi;
    drow[n] = rl * wi;
  }
}

// ---------- 4. colpass: partial[by][m] = sum_{n in chunk} t[n][m] * winv[n] ----------
__global__ __launch_bounds__(256) void colpass_kernel(
    const unsigned short* __restrict__ Tb, const float* __restrict__ winv,
    float* __restrict__ partial) {
  __shared__ float w[64];
  int b = blockIdx.x, tid = threadIdx.x;
  int bx = b & 7, by = b >> 3;
  int m0 = bx * 512 + tid * 2;
  int n0 = by * 64;
  if (tid < 64) w[tid] = winv[n0 + tid];
  __syncthreads();
  float a0 = 0.f, a1 = 0.f;
  #pragma unroll 4
  for (int i = 0; i < 64; ++i) {
    unsigned tv = *(const unsigned*)(Tb + (size_t)(n0 + i) * M_NU + m0);
    float wv = w[i];
    a0 = fmaf(bf2f((unsigned short)(tv & 0xffffu)), wv, a0);
    a1 = fmaf(bf2f((unsigned short)(tv >> 16)), wv, a1);
  }
  *(float2*)(partial + (size_t)by * M_NU + m0) = make_float2(a0, a1);
}

// ---------- 5. final: blocks 0..15 scaled probs; block 16 scalars + means ----------
__global__ __launch_bounds__(256) void final_kernel(
    const float* __restrict__ partial, const float* __restrict__ trow,
    const float* __restrict__ drow, const float* __restrict__ csum_part,
    float* __restrict__ out) {
  __shared__ float red[4];
  int b = blockIdx.x, tid = threadIdx.x;
  float lt = 0.f;
  for (int i = tid; i < N_PTR; i += 256) lt += trow[i];
  float T = blk_reduce_sum(lt, red);
  float scale = (1.0f / (float)N_PTR) / (T / (float)N_PTR + EPS_);
  if (b < 16) {
    int m = b * 256 + tid;
    float raw = 0.f;
    #pragma unroll
    for (int c = 0; c < 32; ++c) raw += partial[(size_t)c * M_NU + m];
    out[2 + m] = raw * scale;
  } else {
    float ld = 0.f;
    for (int i = tid; i < N_PTR; i += 256) ld += drow[i];
    float D = blk_reduce_sum(ld, red);
    float lx = 0.f, ly = 0.f;
    for (int c = tid; c < DIM; c += 256) {
      float sA = 0.f, sB = 0.f, sPe = 0.f, sQe = 0.f;
      #pragma unroll 4
      for (int p = 0; p < 16; ++p)  sA  += csum_part[(size_t)p * DIM + c];
      #pragma unroll 4
      for (int p = 16; p < 48; ++p) sB  += csum_part[(size_t)p * DIM + c];
      #pragma unroll 4
      for (int p = 48; p < 64; ++p) sPe += csum_part[(size_t)p * DIM + c];
      #pragma unroll 4
      for (int p = 64; p < 96; ++p) sQe += csum_part[(size_t)p * DIM + c];
      lx = fmaf(sA, sB, lx);
      ly = fmaf(sPe, sQe, ly);
    }
    float dX = blk_reduce_sum(lx, red);
    float dY = blk_reduce_sum(ly, red);
    if (tid == 0) {
      float dro = D * scale;
      const float invNM = 1.0f / ((float)N_PTR * (float)M_NU);
      float mcx = 1.f - dX * invNM;
      float mcy = 1.f - dY * invNM;
      out[0] = dro;
      out[1] = dro;
      out[2 + M_NU] = mcx + mcy;
      out[3 + M_NU] = mcx;
      out[4 + M_NU] = mcy;
    }
  }
}

extern "C" void kernel_launch(void* const* d_in, const int* in_sizes, int n_in,
                              void* d_out, int out_size, void* d_ws, size_t ws_size,
                              hipStream_t stream) {
  const float* ptr_feat = (const float*)d_in[0];
  const int*   ptr_lab  = (const int*)d_in[2];
  const float* nu_feat  = (const float*)d_in[3];
  const float* nu_log   = (const float*)d_in[4];
  const int*   nu_lab   = (const int*)d_in[5];
  const float* cls_w    = (const float*)d_in[6];
  float* out = (float*)d_out;

  char* base = (char*)d_ws;
  unsigned short* Sb  = (unsigned short*)base;                         // 16 MB (s, then t in-place)
  unsigned short* Gfb = (unsigned short*)(base + 16u * 1024 * 1024);   // 2 MB bf16 gram
  unsigned short* An  = (unsigned short*)(base + 18u * 1024 * 1024);   // 2 MB
  unsigned short* Bn  = (unsigned short*)(base + 20u * 1024 * 1024);   // 4 MB
  unsigned short* Cn  = (unsigned short*)(base + 24u * 1024 * 1024);   // 1 MB
  float* fb           = (float*)(base + 25u * 1024 * 1024);
  float* nloss     = fb;                            // 4096
  unsigned* gbits  = (unsigned*)(nloss + 4096);     // 1 (+63 pad)
  float* winv      = nloss + 4096 + 64;             // 2048
  float* trow      = winv + N_PTR;                  // 2048
  float* drow      = trow + N_PTR;                  // 2048
  float* partial   = drow + N_PTR;                  // 32 * 4096
  float* csum_part = partial + 32 * M_NU;           // 96 * 512

  prep_kernel<<<dim3(1792 + M_NU), 256, 0, stream>>>(
      ptr_feat, nu_feat, cls_w, nu_log, nu_lab, An, Bn, Cn, nloss);
  gemm_kernel<128, 32, 0><<<dim3(512), 256, 0, stream>>>(
      An, Bn, Sb, M_NU, nullptr, nullptr, nullptr, nullptr, nullptr,
      nullptr, nullptr, nullptr);
  gemm_kernel<64, 16, 1><<<dim3(256 + 97), 256, 0, stream>>>(
      Cn, Cn, Gfb, KPAD, An, Bn, Cn, ptr_lab, nu_lab, nloss, csum_part, gbits);
  rowpass_kernel<<<dim3(N_PTR / 4), 256, 0, stream>>>(
      Sb, Gfb, ptr_lab, nu_lab, nloss, gbits, winv, trow, drow);
  colpass_kernel<<<dim3(256), 256, 0, stream>>>(Sb, winv, partial);
  final_kernel<<<dim3(17), 256, 0, stream>>>(partial, trow, drow, csum_part, out);
}